// Round 6
// baseline (491.252 us; speedup 1.0000x reference)
//
#include <hip/hip_runtime.h>
#include <cstdint>
#include <cstddef>

typedef _Float16 f16;
typedef f16 f16x8 __attribute__((ext_vector_type(8)));
typedef float f32x4 __attribute__((ext_vector_type(4)));
typedef float f32x16 __attribute__((ext_vector_type(16)));

#define B_ROWS 65536
#define NT_BRANCH 1030   // 64-row branch tiles: 1024 + 6 bins' padding
#define NT_SPEED 1024    // 64-row speed tiles

// ---------------- ws layout ----------------
constexpr size_t OFF_SF16   = 0;
constexpr size_t SZ_SF16    = (size_t)B_ROWS * 128 * 2;
constexpr size_t OFF_SIW2T  = OFF_SF16 + SZ_SF16;
constexpr size_t SZ_SIW2T   = (size_t)128 * 256 * 2;
constexpr size_t OFF_BW1T   = OFF_SIW2T + SZ_SIW2T;
constexpr size_t SZ_BW1T    = (size_t)6 * 256 * 640 * 2;
constexpr size_t OFF_BW2T   = OFF_BW1T + SZ_BW1T;
constexpr size_t SZ_BW2T    = (size_t)6 * 256 * 256 * 2;
constexpr size_t OFF_SOW1T  = OFF_BW2T + SZ_BW2T;
constexpr size_t SZ_SOW1T   = (size_t)256 * 640 * 2;
constexpr size_t OFF_SOW2T  = OFF_SOW1T + SZ_SOW1T;
constexpr size_t SZ_SOW2T   = (size_t)256 * 256 * 2;
constexpr size_t OFF_BW3T16 = OFF_SOW2T + SZ_SOW2T;
constexpr size_t SZ_BW3T16  = (size_t)6 * 16 * 256 * 2;
constexpr size_t OFF_SOW3T16= OFF_BW3T16 + SZ_BW3T16;
constexpr size_t SZ_SOW3T16 = (size_t)16 * 256 * 2;
constexpr size_t OFF_COUNTS = OFF_SOW3T16 + SZ_SOW3T16;
constexpr size_t OFF_CURSORS= OFF_COUNTS + 256;
constexpr size_t OFF_TILECMD= OFF_CURSORS + 256;
constexpr size_t OFF_PERM   = OFF_TILECMD + 4352;
constexpr size_t WS_NEEDED  = OFF_PERM + (size_t)NT_BRANCH * 64 * 4;

// ---------------- prep: transpose-cast weights + W3T16 + init sort scratch ----------------
__global__ void prep_kernel(const float* __restrict__ siW2,
                            const float* __restrict__ bW1,
                            const float* __restrict__ bW2,
                            const float* __restrict__ soW1,
                            const float* __restrict__ soW2,
                            const float* __restrict__ bW3,
                            const float* __restrict__ soW3,
                            f16* __restrict__ siW2T, f16* __restrict__ bW1T,
                            f16* __restrict__ bW2T, f16* __restrict__ soW1T,
                            f16* __restrict__ soW2T,
                            f16* __restrict__ bW3T16, f16* __restrict__ soW3T16,
                            int* __restrict__ counts, int* __restrict__ cursors,
                            int* __restrict__ perm)
{
    const int bx = blockIdx.x;
    const int tx = threadIdx.x, ty = threadIdx.y;
    const int tid = ty * 32 + tx;
    if (bx >= 1601) {                       // perm init + counter zero
        const int ib = bx - 1601;
        const int idx = ib * 256 + tid;
        if (idx < NT_BRANCH * 64) perm[idx] = -1;
        if (ib == 0 && tid < 6) { counts[tid] = 0; cursors[tid] = 0; }
        return;
    }
    if (bx == 1600) {                       // W3 -> padded-16-col f16, [n][k] layout
        for (int i = tid; i < 6 * 16 * 256; i += 256) {
            const int c = i >> 12, rem = i & 4095, n = rem >> 8, k = rem & 255;
            bW3T16[i] = (n < 3) ? (f16)bW3[((size_t)c * 256 + k) * 3 + n] : (f16)0;
        }
        for (int i = tid; i < 16 * 256; i += 256) {
            const int n = i >> 8, k = i & 255;
            soW3T16[i] = (n == 0) ? (f16)soW3[k] : (f16)0;
        }
        return;
    }
    const float* in; f16* out; int R, C, lb;
    if (bx < 960)       { int m = bx / 160;        lb = bx - m * 160;       in = bW1 + (size_t)m * 640 * 256; out = bW1T + (size_t)m * 640 * 256; R = 640; C = 256; }
    else if (bx < 1344) { int m = (bx - 960) / 64; lb = (bx - 960) - m * 64; in = bW2 + (size_t)m * 256 * 256; out = bW2T + (size_t)m * 256 * 256; R = 256; C = 256; }
    else if (bx < 1504) { lb = bx - 1344; in = soW1; out = soW1T; R = 640; C = 256; }
    else if (bx < 1568) { lb = bx - 1504; in = soW2; out = soW2T; R = 256; C = 256; }
    else                { lb = bx - 1568; in = siW2; out = siW2T; R = 256; C = 128; }
    const int txt = C >> 5;
    const int c0 = (lb % txt) << 5;
    const int r0 = (lb / txt) << 5;
    __shared__ float tile[32][33];
    #pragma unroll
    for (int i = 0; i < 4; ++i)
        tile[tx][ty + 8 * i] = in[(size_t)(r0 + ty + 8 * i) * C + c0 + tx];
    __syncthreads();
    #pragma unroll
    for (int i = 0; i < 4; ++i)
        out[(size_t)(c0 + ty + 8 * i) * R + r0 + tx] = (f16)tile[ty + 8 * i][tx];
}

// ---------------- speed_in MLP (+ fused histogram) ----------------
__global__ __launch_bounds__(256) void speedin_kernel(
    const float* __restrict__ speed,
    const float* __restrict__ siW1, const float* __restrict__ sib1,
    const f16* __restrict__ siW2T, const float* __restrict__ sib2,
    const int* __restrict__ cmd,
    f16* __restrict__ sF16, int* __restrict__ counts)
{
    __shared__ f16 H[64 * 264];
    __shared__ float spd[64];
    __shared__ int h[6];
    const int tid = threadIdx.x;
    const int rb = blockIdx.x * 64;
    if (tid < 6) h[tid] = 0;
    __syncthreads();
    if (tid < 64) {
        spd[tid] = speed[rb + tid];
        atomicAdd(&h[cmd[rb + tid] - 1], 1);
    }
    __syncthreads();
    if (tid < 6 && h[tid] > 0) atomicAdd(&counts[tid], h[tid]);
    {
        const float w1 = siW1[tid], b1v = sib1[tid];
        #pragma unroll 4
        for (int r = 0; r < 64; ++r) {
            float hv = spd[r] * w1 + b1v;
            H[r * 264 + tid] = (f16)(hv > 0.f ? hv : 0.f);
        }
    }
    __syncthreads();
    const int w = tid >> 6, lane = tid & 63, lq = lane >> 4, l16 = lane & 15;
    const int nb = w * 32;
    f32x4 acc[4][2];
    #pragma unroll
    for (int mt = 0; mt < 4; ++mt)
        #pragma unroll
        for (int nt = 0; nt < 2; ++nt)
            acc[mt][nt] = (f32x4){0.f, 0.f, 0.f, 0.f};
    for (int ks = 0; ks < 8; ++ks) {
        const int koff = ks * 32 + lq * 8;
        f16x8 af[4], bf[2];
        #pragma unroll
        for (int mt = 0; mt < 4; ++mt)
            af[mt] = *(const f16x8*)(&H[(mt * 16 + l16) * 264 + koff]);
        #pragma unroll
        for (int nt = 0; nt < 2; ++nt)
            bf[nt] = *(const f16x8*)(siW2T + (size_t)(nb + nt * 16 + l16) * 256 + koff);
        #pragma unroll
        for (int mt = 0; mt < 4; ++mt)
            #pragma unroll
            for (int nt = 0; nt < 2; ++nt)
                acc[mt][nt] = __builtin_amdgcn_mfma_f32_16x16x32_f16(af[mt], bf[nt], acc[mt][nt], 0, 0, 0);
    }
    #pragma unroll
    for (int mt = 0; mt < 4; ++mt)
        #pragma unroll
        for (int nt = 0; nt < 2; ++nt) {
            const int n = nb + nt * 16 + l16;
            const float bv = sib2[n];
            #pragma unroll
            for (int r2 = 0; r2 < 4; ++r2) {
                const int m = mt * 16 + lq * 4 + r2;
                sF16[(size_t)(rb + m) * 128 + n] = (f16)(acc[mt][nt][r2] + bv);
            }
        }
}

// ---------------- place (plan fused): scatter rows into 64-padded bins + tile_cmd ----------------
__global__ void place_kernel(const int* __restrict__ cmd,
                             const int* __restrict__ counts,
                             int* __restrict__ cursors, int* __restrict__ perm,
                             int* __restrict__ tile_cmd) {
    __shared__ int lcnt[6], lbase[6], bb[7];
    const int tid = threadIdx.x;
    if (tid < 6) lcnt[tid] = 0;
    __syncthreads();
    const int i = blockIdx.x * 256 + tid;
    const int c = cmd[i] - 1;
    const int myr = atomicAdd(&lcnt[c], 1);
    if (tid == 0) {
        int base = 0;
        for (int c0 = 0; c0 < 6; ++c0) {
            bb[c0] = base;
            base += ((counts[c0] + 63) >> 6) << 6;
        }
        bb[6] = base;
    }
    __syncthreads();
    if (tid < 6) lbase[tid] = atomicAdd(&cursors[tid], lcnt[tid]);
    __syncthreads();
    perm[bb[c] + lbase[c] + myr] = i;
    if (blockIdx.x == 0) {
        for (int t = tid; t < NT_BRANCH; t += 256) {
            int cc = -1;
            #pragma unroll
            for (int j = 0; j < 6; ++j)
                if (t * 64 >= bb[j] && t * 64 < bb[j + 1]) cc = j;
            tile_cmd[t] = cc;
        }
    }
}

// ---------------- heads: M=64 tile, K-halved burst staging, 32x32 MFMA ----------------
// 512 thr = 8 waves; wave w owns cols nb=w*32; acc0=rows 0-31, acc1=rows 32-63.
// A [64][324] f16 in LDS (stride 324: 2-way bank alias = free); h aliases at [64][268].
// GEMM1: two K-halves of 320, each staged in one burst (one vmcnt drain per half).
// B rolled 8 deep (32 VGPR) from L2-resident weights.
__global__ __launch_bounds__(512, 4) void heads_kernel(
    const float* __restrict__ emb,        // [B,512] fp32
    const f16* __restrict__ sF16,         // [B,128]
    const int* __restrict__ perm, const int* __restrict__ tile_cmd,
    const f16* __restrict__ bW1T, const f16* __restrict__ bW2T,
    const f16* __restrict__ bW3T16,
    const float* __restrict__ bb1, const float* __restrict__ bb2,
    const float* __restrict__ bb3,
    const f16* __restrict__ soW1T, const f16* __restrict__ soW2T,
    const f16* __restrict__ soW3T16,
    const float* __restrict__ sob1, const float* __restrict__ sob2,
    const float* __restrict__ sob3,
    float* __restrict__ out)
{
    __shared__ f16 smem[64 * 324];        // A halves; h [64][268] aliases
    __shared__ int rowIdx[64];
    const int bx = blockIdx.x, tid = threadIdx.x;
    const bool is_speed = (bx < NT_SPEED);
    const f16 *W1T, *W2T, *W3T;
    const float *bias1, *bias2, *bias3;
    if (is_speed) {
        if (tid < 64) rowIdx[tid] = bx * 64 + tid;
        W1T = soW1T; W2T = soW2T; W3T = soW3T16;
        bias1 = sob1; bias2 = sob2; bias3 = sob3;
    } else {
        const int t = bx - NT_SPEED;
        const int c = tile_cmd[t];
        if (c < 0) return;
        if (tid < 64) rowIdx[tid] = perm[t * 64 + tid];
        W1T = bW1T + (size_t)c * 256 * 640;
        W2T = bW2T + (size_t)c * 256 * 256;
        W3T = bW3T16 + (size_t)c * 16 * 256;
        bias1 = bb1 + c * 256; bias2 = bb2 + c * 256; bias3 = bb3 + c * 3;
    }
    __syncthreads();

    const int w = tid >> 6, lane = tid & 63;
    const int l32 = lane & 31, lq2 = lane >> 5;
    const int l16 = lane & 15, lq = lane >> 4;
    const int nb = w * 32;

    // staging role: row r (8 threads/row), 8-col group p
    const int r = tid >> 3, p = tid & 7;
    int g = rowIdx[r]; if (g < 0) g = 0;
    const float* srcF = emb + (size_t)g * 512;
    const f16*   srcH = sF16 + (size_t)g * 128;
    f16* dst = smem + r * 324 + p * 8;

    // B / bias pointers
    const f16* bp = W1T + (size_t)(nb + l32) * 640 + lq2 * 8;
    const float b1v = bias1[nb + l32];
    const float b2v = bias2[nb + l32];
    const f16* aB0 = smem + l32 * 324 + lq2 * 8;
    const f16* aB1 = smem + (32 + l32) * 324 + lq2 * 8;

    f32x16 acc0, acc1;
    #pragma unroll
    for (int i = 0; i < 16; ++i) { acc0[i] = 0.f; acc1[i] = 0.f; }

    f16x8 Bb[8];
    #pragma unroll
    for (int half = 0; half < 2; ++half) {
        // ---- stage this K-half (5 chunks of 64 cols) in one burst
        {
            const int cb = half * 320;
            float4 fa[5], fb[5];
            f16x8 hv[2];
            int nf = 0, nh = 0;
            #pragma unroll
            for (int c = 0; c < 5; ++c) {
                const int col = cb + c * 64 + p * 8;
                if (col < 512) {
                    fa[nf] = ((const float4*)(srcF + col))[0];
                    fb[nf] = ((const float4*)(srcF + col))[1];
                    ++nf;
                } else {
                    hv[nh++] = *(const f16x8*)(srcH + (col - 512));
                }
            }
            // prefill B window for this half while loads are in flight
            #pragma unroll
            for (int si = 0; si < 8; ++si)
                Bb[si] = *(const f16x8*)(bp + half * 320 + si * 16);
            nf = 0; nh = 0;
            #pragma unroll
            for (int c = 0; c < 5; ++c) {
                const int col = cb + c * 64 + p * 8;
                f16x8 v;
                if (col < 512) {
                    v[0] = (f16)fa[nf].x; v[1] = (f16)fa[nf].y; v[2] = (f16)fa[nf].z; v[3] = (f16)fa[nf].w;
                    v[4] = (f16)fb[nf].x; v[5] = (f16)fb[nf].y; v[6] = (f16)fb[nf].z; v[7] = (f16)fb[nf].w;
                    ++nf;
                } else {
                    v = hv[nh++];
                }
                *(f16x8*)(dst + c * 64) = v;
            }
        }
        __syncthreads();                  // A half ready (single drain)
        // ---- 20 MFMA steps, no barriers
        const f16* bph = bp + half * 320;
        #pragma unroll
        for (int s = 0; s < 20; ++s) {
            const int si = s & 7;
            const f16x8 a0 = *(const f16x8*)(aB0 + s * 16);
            const f16x8 a1 = *(const f16x8*)(aB1 + s * 16);
            acc0 = __builtin_amdgcn_mfma_f32_32x32x16_f16(a0, Bb[si], acc0, 0, 0, 0);
            acc1 = __builtin_amdgcn_mfma_f32_32x32x16_f16(a1, Bb[si], acc1, 0, 0, 0);
            if (s < 12)
                Bb[si] = *(const f16x8*)(bph + (s + 8) * 16);
        }
        __syncthreads();                  // all reads of this half done
    }

    // GEMM2 B prefill (ages across the h1 epilogue)
    const f16* cp = W2T + (size_t)(nb + l32) * 256 + lq2 * 8;
    f16x8 Cb[8];
    #pragma unroll
    for (int si = 0; si < 8; ++si)
        Cb[si] = *(const f16x8*)(cp + si * 16);

    // h1 = relu(acc + b1) -> smem[64][268]  (32x32 C-layout; col=nb+l32)
    #pragma unroll
    for (int rg = 0; rg < 16; ++rg) {
        const int m = (rg & 3) + 8 * (rg >> 2) + 4 * lq2;
        const float v0 = acc0[rg] + b1v;
        const float v1 = acc1[rg] + b1v;
        smem[m * 268 + nb + l32]        = (f16)(v0 > 0.f ? v0 : 0.f);
        smem[(m + 32) * 268 + nb + l32] = (f16)(v1 > 0.f ? v1 : 0.f);
    }
    __syncthreads();

    // ---- GEMM2: K=256 = 16 steps, no barriers
    f32x16 d0, d1;
    #pragma unroll
    for (int i = 0; i < 16; ++i) { d0[i] = 0.f; d1[i] = 0.f; }
    const f16* hB0 = smem + l32 * 268 + lq2 * 8;
    const f16* hB1 = smem + (32 + l32) * 268 + lq2 * 8;
    #pragma unroll
    for (int s = 0; s < 16; ++s) {
        const int si = s & 7;
        const f16x8 a0 = *(const f16x8*)(hB0 + s * 16);
        const f16x8 a1 = *(const f16x8*)(hB1 + s * 16);
        d0 = __builtin_amdgcn_mfma_f32_32x32x16_f16(a0, Cb[si], d0, 0, 0, 0);
        d1 = __builtin_amdgcn_mfma_f32_32x32x16_f16(a1, Cb[si], d1, 0, 0, 0);
        if (s < 8)
            Cb[si] = *(const f16x8*)(cp + (s + 8) * 16);
    }
    __syncthreads();
    // h2 = relu(d + b2) -> smem[64][268]
    #pragma unroll
    for (int rg = 0; rg < 16; ++rg) {
        const int m = (rg & 3) + 8 * (rg >> 2) + 4 * lq2;
        const float v0 = d0[rg] + b2v;
        const float v1 = d1[rg] + b2v;
        smem[m * 268 + nb + l32]        = (f16)(v0 > 0.f ? v0 : 0.f);
        smem[(m + 32) * 268 + nb + l32] = (f16)(v1 > 0.f ? v1 : 0.f);
    }
    __syncthreads();
    // ---- GEMM3: [64,256]@[256,16] via 16x16x32; waves 0-3 own 16-row slices
    if (w < 4) {
        f32x4 acc3 = (f32x4){0.f, 0.f, 0.f, 0.f};
        const f16* w3row = W3T + (size_t)l16 * 256 + lq * 8;
        const f16* h2row = smem + (w * 16 + l16) * 268 + lq * 8;
        #pragma unroll
        for (int ks = 0; ks < 8; ++ks) {
            const f16x8 af = *(const f16x8*)(h2row + ks * 32);
            const f16x8 bf = *(const f16x8*)(w3row + ks * 32);
            acc3 = __builtin_amdgcn_mfma_f32_16x16x32_f16(af, bf, acc3, 0, 0, 0);
        }
        const int orow = w * 16 + lq * 4;
        if (!is_speed) {
            if (l16 < 3) {
                const float b3 = bias3[l16];
                #pragma unroll
                for (int r2 = 0; r2 < 4; ++r2) {
                    const int g2 = rowIdx[orow + r2];
                    if (g2 >= 0)
                        out[(size_t)g2 * 3 + l16] = 1.f / (1.f + __expf(-(acc3[r2] + b3)));
                }
            }
        } else if (l16 == 0) {
            const float b3 = bias3[0];
            #pragma unroll
            for (int r2 = 0; r2 < 4; ++r2)
                out[(size_t)3 * B_ROWS + rowIdx[orow + r2]] = acc3[r2] + b3;
        }
    }
}

extern "C" void kernel_launch(void* const* d_in, const int* in_sizes, int n_in,
                              void* d_out, int out_size, void* d_ws, size_t ws_size,
                              hipStream_t stream) {
    (void)in_sizes; (void)n_in; (void)out_size; (void)ws_size;
    const float* embedding = (const float*)d_in[0];
    const float* speed     = (const float*)d_in[1];
    const int*   command   = (const int*)d_in[2];
    const float* si_W1 = (const float*)d_in[3];
    const float* si_b1 = (const float*)d_in[4];
    const float* si_W2 = (const float*)d_in[5];
    const float* si_b2 = (const float*)d_in[6];
    const float* bW1   = (const float*)d_in[7];
    const float* bb1   = (const float*)d_in[8];
    const float* bW2   = (const float*)d_in[9];
    const float* bb2   = (const float*)d_in[10];
    const float* bW3   = (const float*)d_in[11];
    const float* bb3   = (const float*)d_in[12];
    const float* so_W1 = (const float*)d_in[13];
    const float* so_b1 = (const float*)d_in[14];
    const float* so_W2 = (const float*)d_in[15];
    const float* so_b2 = (const float*)d_in[16];
    const float* so_W3 = (const float*)d_in[17];
    const float* so_b3 = (const float*)d_in[18];
    float* out = (float*)d_out;

    char* ws = (char*)d_ws;
    f16* sF16   = (f16*)(ws + OFF_SF16);
    f16* siW2T  = (f16*)(ws + OFF_SIW2T);
    f16* bW1T   = (f16*)(ws + OFF_BW1T);
    f16* bW2T   = (f16*)(ws + OFF_BW2T);
    f16* soW1T  = (f16*)(ws + OFF_SOW1T);
    f16* soW2T  = (f16*)(ws + OFF_SOW2T);
    f16* bW3T16 = (f16*)(ws + OFF_BW3T16);
    f16* soW3T16= (f16*)(ws + OFF_SOW3T16);
    int* counts = (int*)(ws + OFF_COUNTS);
    int* cursors= (int*)(ws + OFF_CURSORS);
    int* tile_cmd = (int*)(ws + OFF_TILECMD);
    int* perm   = (int*)(ws + OFF_PERM);

    prep_kernel<<<1859, dim3(32, 8), 0, stream>>>(
        si_W2, bW1, bW2, so_W1, so_W2, bW3, so_W3,
        siW2T, bW1T, bW2T, soW1T, soW2T, bW3T16, soW3T16,
        counts, cursors, perm);
    speedin_kernel<<<1024, 256, 0, stream>>>(
        speed, si_W1, si_b1, siW2T, si_b2, command, sF16, counts);
    place_kernel<<<256, 256, 0, stream>>>(command, counts, cursors, perm, tile_cmd);
    heads_kernel<<<NT_SPEED + NT_BRANCH, 512, 0, stream>>>(
        embedding, sF16, perm, tile_cmd,
        bW1T, bW2T, bW3T16, bb1, bb2, bb3,
        soW1T, soW2T, soW3T16, so_b1, so_b2, so_b3, out);
}

// Round 7
// 470.597 us; speedup vs baseline: 1.0439x; 1.0439x over previous
//
#include <hip/hip_runtime.h>
#include <cstdint>
#include <cstddef>

typedef _Float16 f16;
typedef f16 f16x8 __attribute__((ext_vector_type(8)));
typedef float f32x4 __attribute__((ext_vector_type(4)));
typedef float f32x16 __attribute__((ext_vector_type(16)));

#define B_ROWS 65536
#define NT 1030                // 64-row tiles incl. bin padding
#define NROWS_P (NT * 64)      // 65920 padded rows

// ---------------- ws layout ----------------
constexpr size_t OFF_EMBF16 = 0;
constexpr size_t SZ_EMBF16  = (size_t)NROWS_P * 640 * 2;       // 84,377,600
constexpr size_t OFF_SIW2T  = OFF_EMBF16 + SZ_EMBF16;
constexpr size_t SZ_SIW2T   = (size_t)128 * 256 * 2;
constexpr size_t OFF_BW1T   = OFF_SIW2T + SZ_SIW2T;
constexpr size_t SZ_BW1T    = (size_t)6 * 256 * 640 * 2;
constexpr size_t OFF_BW2T   = OFF_BW1T + SZ_BW1T;
constexpr size_t SZ_BW2T    = (size_t)6 * 256 * 256 * 2;
constexpr size_t OFF_SOW1T  = OFF_BW2T + SZ_BW2T;
constexpr size_t SZ_SOW1T   = (size_t)256 * 640 * 2;
constexpr size_t OFF_SOW2T  = OFF_SOW1T + SZ_SOW1T;
constexpr size_t SZ_SOW2T   = (size_t)256 * 256 * 2;
constexpr size_t OFF_BW3T16 = OFF_SOW2T + SZ_SOW2T;
constexpr size_t SZ_BW3T16  = (size_t)6 * 16 * 256 * 2;
constexpr size_t OFF_SOW3T16= OFF_BW3T16 + SZ_BW3T16;
constexpr size_t SZ_SOW3T16 = (size_t)16 * 256 * 2;
constexpr size_t OFF_COUNTS = OFF_SOW3T16 + SZ_SOW3T16;
constexpr size_t OFF_CURSORS= OFF_COUNTS + 256;
constexpr size_t OFF_TILECMD= OFF_CURSORS + 256;
constexpr size_t OFF_PERM   = OFF_TILECMD + 4352;
constexpr size_t WS_NEEDED  = OFF_PERM + (size_t)NROWS_P * 4;  // ~88 MB

// async 16B global -> LDS DMA (lane i of the wave lands at ldsbase + 16*i)
__device__ __forceinline__ void gload_lds16(const void* g, void* l) {
    __builtin_amdgcn_global_load_lds(
        (const __attribute__((address_space(1))) unsigned int*)g,
        (__attribute__((address_space(3))) unsigned int*)l, 16, 0, 0);
}

// ---------------- prep: transpose-cast weights + W3T16 + init sort scratch ----------------
__global__ void prep_kernel(const float* __restrict__ siW2,
                            const float* __restrict__ bW1,
                            const float* __restrict__ bW2,
                            const float* __restrict__ soW1,
                            const float* __restrict__ soW2,
                            const float* __restrict__ bW3,
                            const float* __restrict__ soW3,
                            f16* __restrict__ siW2T, f16* __restrict__ bW1T,
                            f16* __restrict__ bW2T, f16* __restrict__ soW1T,
                            f16* __restrict__ soW2T,
                            f16* __restrict__ bW3T16, f16* __restrict__ soW3T16,
                            int* __restrict__ counts, int* __restrict__ cursors,
                            int* __restrict__ perm)
{
    const int bx = blockIdx.x;
    const int tx = threadIdx.x, ty = threadIdx.y;
    const int tid = ty * 32 + tx;
    if (bx >= 1601) {                       // perm init + counter zero
        const int ib = bx - 1601;
        const int idx = ib * 256 + tid;
        if (idx < NROWS_P) perm[idx] = -1;
        if (ib == 0 && tid < 6) { counts[tid] = 0; cursors[tid] = 0; }
        return;
    }
    if (bx == 1600) {                       // W3 -> padded-16-col f16, [n][k] layout
        for (int i = tid; i < 6 * 16 * 256; i += 256) {
            const int c = i >> 12, rem = i & 4095, n = rem >> 8, k = rem & 255;
            bW3T16[i] = (n < 3) ? (f16)bW3[((size_t)c * 256 + k) * 3 + n] : (f16)0;
        }
        for (int i = tid; i < 16 * 256; i += 256) {
            const int n = i >> 8, k = i & 255;
            soW3T16[i] = (n == 0) ? (f16)soW3[k] : (f16)0;
        }
        return;
    }
    const float* in; f16* out; int R, C, lb;
    if (bx < 960)       { int m = bx / 160;        lb = bx - m * 160;       in = bW1 + (size_t)m * 640 * 256; out = bW1T + (size_t)m * 640 * 256; R = 640; C = 256; }
    else if (bx < 1344) { int m = (bx - 960) / 64; lb = (bx - 960) - m * 64; in = bW2 + (size_t)m * 256 * 256; out = bW2T + (size_t)m * 256 * 256; R = 256; C = 256; }
    else if (bx < 1504) { lb = bx - 1344; in = soW1; out = soW1T; R = 640; C = 256; }
    else if (bx < 1568) { lb = bx - 1504; in = soW2; out = soW2T; R = 256; C = 256; }
    else                { lb = bx - 1568; in = siW2; out = siW2T; R = 256; C = 128; }
    const int txt = C >> 5;
    const int c0 = (lb % txt) << 5;
    const int r0 = (lb / txt) << 5;
    __shared__ float tile[32][33];
    #pragma unroll
    for (int i = 0; i < 4; ++i)
        tile[tx][ty + 8 * i] = in[(size_t)(r0 + ty + 8 * i) * C + c0 + tx];
    __syncthreads();
    #pragma unroll
    for (int i = 0; i < 4; ++i)
        out[(size_t)(c0 + ty + 8 * i) * R + r0 + tx] = (f16)tile[ty + 8 * i][tx];
}

// ---------------- hist ----------------
__global__ void hist_kernel(const int* __restrict__ cmd, int* __restrict__ counts) {
    __shared__ int h[6];
    const int tid = threadIdx.x;
    if (tid < 6) h[tid] = 0;
    __syncthreads();
    atomicAdd(&h[cmd[blockIdx.x * 256 + tid] - 1], 1);
    __syncthreads();
    if (tid < 6 && h[tid] > 0) atomicAdd(&counts[tid], h[tid]);
}

// ---------------- place: scatter rows into 64-padded bins + tile_cmd ----------------
__global__ void place_kernel(const int* __restrict__ cmd,
                             const int* __restrict__ counts,
                             int* __restrict__ cursors, int* __restrict__ perm,
                             int* __restrict__ tile_cmd) {
    __shared__ int lcnt[6], lbase[6], bb[7];
    const int tid = threadIdx.x;
    if (tid < 6) lcnt[tid] = 0;
    __syncthreads();
    const int i = blockIdx.x * 256 + tid;
    const int c = cmd[i] - 1;
    const int myr = atomicAdd(&lcnt[c], 1);
    if (tid == 0) {
        int base = 0;
        for (int c0 = 0; c0 < 6; ++c0) {
            bb[c0] = base;
            base += ((counts[c0] + 63) >> 6) << 6;
        }
        bb[6] = base;
    }
    __syncthreads();
    if (tid < 6) lbase[tid] = atomicAdd(&cursors[tid], lcnt[tid]);
    __syncthreads();
    perm[bb[c] + lbase[c] + myr] = i;
    if (blockIdx.x == 0) {
        for (int t = tid; t < NT; t += 256) {
            int cc = -1;
            #pragma unroll
            for (int j = 0; j < 6; ++j)
                if (t * 64 >= bb[j] && t * 64 < bb[j + 1]) cc = j;
            tile_cmd[t] = cc;
        }
    }
}

// ---------------- pack: embF16[perm-ordered rows] = [cast(emb) | speed_in MLP] ----------------
__global__ __launch_bounds__(256) void pack_kernel(
    const float* __restrict__ emb, const float* __restrict__ speed,
    const float* __restrict__ siW1, const float* __restrict__ sib1,
    const f16* __restrict__ siW2T, const float* __restrict__ sib2,
    const int* __restrict__ perm,
    f16* __restrict__ embF16)
{
    __shared__ f16 H[64 * 264];
    __shared__ int rIdx[64];
    __shared__ float spd[64];
    const int tid = threadIdx.x;
    const int t = blockIdx.x;
    if (tid < 64) {
        int g = perm[t * 64 + tid];
        if (g < 0) g = 0;
        rIdx[tid] = g;
        spd[tid] = speed[g];
    }
    __syncthreads();
    {   // speed_in hidden layer (K=1)
        const float w1 = siW1[tid], b1v = sib1[tid];
        #pragma unroll 4
        for (int r = 0; r < 64; ++r) {
            float hv = spd[r] * w1 + b1v;
            H[r * 264 + tid] = (f16)(hv > 0.f ? hv : 0.f);
        }
    }
    // cast-copy cols 0..511 (perm-gathered rows; coalesced within row)
    {
        const int r = tid >> 2, q = tid & 3;
        const float* src = emb + (size_t)rIdx[r] * 512 + q * 128;
        f16* dstp = embF16 + (size_t)(t * 64 + r) * 640 + q * 128;
        #pragma unroll
        for (int i = 0; i < 16; ++i) {
            const float4 f0 = ((const float4*)src)[2 * i];
            const float4 f1 = ((const float4*)src)[2 * i + 1];
            f16x8 v;
            v[0] = (f16)f0.x; v[1] = (f16)f0.y; v[2] = (f16)f0.z; v[3] = (f16)f0.w;
            v[4] = (f16)f1.x; v[5] = (f16)f1.y; v[6] = (f16)f1.z; v[7] = (f16)f1.w;
            *(f16x8*)(dstp + i * 8) = v;
        }
    }
    __syncthreads();
    // layer 2: [64,256]@[256,128] MFMA -> cols 512..639
    const int w = tid >> 6, lane = tid & 63, lq = lane >> 4, l16 = lane & 15;
    const int nb = w * 32;
    f32x4 acc[4][2];
    #pragma unroll
    for (int mt = 0; mt < 4; ++mt)
        #pragma unroll
        for (int nt = 0; nt < 2; ++nt)
            acc[mt][nt] = (f32x4){0.f, 0.f, 0.f, 0.f};
    for (int ks = 0; ks < 8; ++ks) {
        const int koff = ks * 32 + lq * 8;
        f16x8 af[4], bf[2];
        #pragma unroll
        for (int mt = 0; mt < 4; ++mt)
            af[mt] = *(const f16x8*)(&H[(mt * 16 + l16) * 264 + koff]);
        #pragma unroll
        for (int nt = 0; nt < 2; ++nt)
            bf[nt] = *(const f16x8*)(siW2T + (size_t)(nb + nt * 16 + l16) * 256 + koff);
        #pragma unroll
        for (int mt = 0; mt < 4; ++mt)
            #pragma unroll
            for (int nt = 0; nt < 2; ++nt)
                acc[mt][nt] = __builtin_amdgcn_mfma_f32_16x16x32_f16(af[mt], bf[nt], acc[mt][nt], 0, 0, 0);
    }
    #pragma unroll
    for (int mt = 0; mt < 4; ++mt)
        #pragma unroll
        for (int nt = 0; nt < 2; ++nt) {
            const int n = nb + nt * 16 + l16;
            const float bv = sib2[n];
            #pragma unroll
            for (int r2 = 0; r2 < 4; ++r2) {
                const int m = mt * 16 + lq * 4 + r2;
                embF16[(size_t)(t * 64 + m) * 640 + 512 + n] = (f16)(acc[mt][nt][r2] + bv);
            }
        }
}

// stage one 64x64 f16 chunk (kc) of the tile into LDS buf via global_load_lds,
// XOR-swizzled on the global side: slot j holds A[r=j>>3][cg=(j&7)^(r&7)]
__device__ __forceinline__ void stage_chunk(const f16* __restrict__ tileBase,
                                            int kc, f16* buf, int tid) {
    #pragma unroll
    for (int round = 0; round < 2; ++round) {
        const int slot = round * 256 + tid;
        const int r = slot >> 3;
        const int cg = (slot & 7) ^ (r & 7);
        const f16* g = tileBase + (size_t)r * 640 + kc * 64 + cg * 8;
        f16* l = buf + (size_t)(round * 256 + (tid & 192)) * 8;   // wave-uniform
        gload_lds16((const void*)g, (void*)l);
    }
}

// ---------------- heads: m97-shaped fused 3-layer MLP ----------------
// 256 thr = 4 waves; wave w owns N cols w*64..+63 (two 32-slabs); M=64 rows.
// Block pairing: bt = bx>>1, odd = speed head, even = branch head (same A-tile -> L2 reuse).
// GEMM1: 10 chunks, LDS dbuf staged by global_load_lds, 1 barrier/chunk,
// 16 mfma_32x32x16 : 8 ds_read_b128 per wave per chunk (m97 ratio).
__global__ __launch_bounds__(256, 4) void heads_kernel(
    const f16* __restrict__ embF16,       // [NROWS_P,640] perm-ordered
    const int* __restrict__ perm, const int* __restrict__ tile_cmd,
    const f16* __restrict__ bW1T, const f16* __restrict__ bW2T,
    const f16* __restrict__ bW3T16,
    const float* __restrict__ bb1, const float* __restrict__ bb2,
    const float* __restrict__ bb3,
    const f16* __restrict__ soW1T, const f16* __restrict__ soW2T,
    const f16* __restrict__ soW3T16,
    const float* __restrict__ sob1, const float* __restrict__ sob2,
    const float* __restrict__ sob3,
    float* __restrict__ out)
{
    __shared__ f16 smem[16896];           // A dbuf 2*4096 f16; h [64][264] aliases
    __shared__ int rowIdx[64];
    const int bx = blockIdx.x, tid = threadIdx.x;
    const int bt = bx >> 1;
    const bool is_speed = (bx & 1);
    const f16 *W1T, *W2T, *W3T;
    const float *bias1, *bias2, *bias3;
    if (is_speed) {
        W1T = soW1T; W2T = soW2T; W3T = soW3T16;
        bias1 = sob1; bias2 = sob2; bias3 = sob3;
    } else {
        const int c = tile_cmd[bt];
        if (c < 0) return;
        W1T = bW1T + (size_t)c * 256 * 640;
        W2T = bW2T + (size_t)c * 256 * 256;
        W3T = bW3T16 + (size_t)c * 16 * 256;
        bias1 = bb1 + c * 256; bias2 = bb2 + c * 256; bias3 = bb3 + c * 3;
    }
    if (tid < 64) rowIdx[tid] = perm[bt * 64 + tid];
    const f16* tileBase = embF16 + (size_t)bt * 64 * 640;

    const int w = tid >> 6, lane = tid & 63;
    const int l32 = lane & 31, lq2 = lane >> 5;
    const int l16 = lane & 15, lq = lane >> 4;
    const int nb = w * 64;

    // ---- GEMM1: K=640, 10 chunks, dbuf, 1 barrier per chunk
    f32x16 acc[2][2];
    #pragma unroll
    for (int mi = 0; mi < 2; ++mi)
        #pragma unroll
        for (int ni = 0; ni < 2; ++ni)
            #pragma unroll
            for (int i = 0; i < 16; ++i)
                acc[mi][ni][i] = 0.f;
    const f16* bpr0 = W1T + (size_t)(nb + l32) * 640 + lq2 * 8;
    const f16* bpr1 = bpr0 + (size_t)32 * 640;
    const int aoff = l32 * 64;            // A row base (f16) in chunk
    const int axor = (l32 & 7);

    stage_chunk(tileBase, 0, smem, tid);
    __syncthreads();
    #pragma unroll 1
    for (int kc = 0; kc < 10; ++kc) {
        const f16* cur = smem + (kc & 1) * 4096;
        if (kc < 9)
            stage_chunk(tileBase, kc + 1, smem + ((kc + 1) & 1) * 4096, tid);
        #pragma unroll
        for (int s = 0; s < 4; ++s) {
            const int cs = ((2 * s + lq2) ^ axor) * 8;
            const f16x8 a0 = *(const f16x8*)(cur + aoff + cs);
            const f16x8 a1 = *(const f16x8*)(cur + aoff + 2048 + cs);
            const f16x8 b0 = *(const f16x8*)(bpr0 + kc * 64 + s * 16);
            const f16x8 b1 = *(const f16x8*)(bpr1 + kc * 64 + s * 16);
            acc[0][0] = __builtin_amdgcn_mfma_f32_32x32x16_f16(a0, b0, acc[0][0], 0, 0, 0);
            acc[1][0] = __builtin_amdgcn_mfma_f32_32x32x16_f16(a1, b0, acc[1][0], 0, 0, 0);
            acc[0][1] = __builtin_amdgcn_mfma_f32_32x32x16_f16(a0, b1, acc[0][1], 0, 0, 0);
            acc[1][1] = __builtin_amdgcn_mfma_f32_32x32x16_f16(a1, b1, acc[1][1], 0, 0, 0);
        }
        __syncthreads();
    }

    // h1 = relu(acc + b1) -> smem [64][264]; 32x32 C-layout
    {
        const float b1v0 = bias1[nb + l32], b1v1 = bias1[nb + 32 + l32];
        #pragma unroll
        for (int mi = 0; mi < 2; ++mi)
            #pragma unroll
            for (int rg = 0; rg < 16; ++rg) {
                const int m = 32 * mi + (rg & 3) + 8 * (rg >> 2) + 4 * lq2;
                const float v0 = acc[mi][0][rg] + b1v0;
                const float v1 = acc[mi][1][rg] + b1v1;
                smem[m * 264 + nb + l32]      = (f16)(v0 > 0.f ? v0 : 0.f);
                smem[m * 264 + nb + 32 + l32] = (f16)(v1 > 0.f ? v1 : 0.f);
            }
    }
    __syncthreads();

    // ---- GEMM2: K=256, A=h1 (LDS), 16 steps, no barriers
    f32x16 d[2][2];
    #pragma unroll
    for (int mi = 0; mi < 2; ++mi)
        #pragma unroll
        for (int ni = 0; ni < 2; ++ni)
            #pragma unroll
            for (int i = 0; i < 16; ++i)
                d[mi][ni][i] = 0.f;
    const f16* cpr0 = W2T + (size_t)(nb + l32) * 256 + lq2 * 8;
    const f16* cpr1 = cpr0 + (size_t)32 * 256;
    const f16* h0 = smem + l32 * 264 + lq2 * 8;
    const f16* h1p = smem + (32 + l32) * 264 + lq2 * 8;
    #pragma unroll
    for (int s = 0; s < 16; ++s) {
        const f16x8 a0 = *(const f16x8*)(h0 + s * 16);
        const f16x8 a1 = *(const f16x8*)(h1p + s * 16);
        const f16x8 b0 = *(const f16x8*)(cpr0 + s * 16);
        const f16x8 b1 = *(const f16x8*)(cpr1 + s * 16);
        d[0][0] = __builtin_amdgcn_mfma_f32_32x32x16_f16(a0, b0, d[0][0], 0, 0, 0);
        d[1][0] = __builtin_amdgcn_mfma_f32_32x32x16_f16(a1, b0, d[1][0], 0, 0, 0);
        d[0][1] = __builtin_amdgcn_mfma_f32_32x32x16_f16(a0, b1, d[0][1], 0, 0, 0);
        d[1][1] = __builtin_amdgcn_mfma_f32_32x32x16_f16(a1, b1, d[1][1], 0, 0, 0);
    }
    __syncthreads();
    // h2 = relu(d + b2) -> smem
    {
        const float b2v0 = bias2[nb + l32], b2v1 = bias2[nb + 32 + l32];
        #pragma unroll
        for (int mi = 0; mi < 2; ++mi)
            #pragma unroll
            for (int rg = 0; rg < 16; ++rg) {
                const int m = 32 * mi + (rg & 3) + 8 * (rg >> 2) + 4 * lq2;
                const float v0 = d[mi][0][rg] + b2v0;
                const float v1 = d[mi][1][rg] + b2v1;
                smem[m * 264 + nb + l32]      = (f16)(v0 > 0.f ? v0 : 0.f);
                smem[m * 264 + nb + 32 + l32] = (f16)(v1 > 0.f ? v1 : 0.f);
            }
    }
    __syncthreads();
    // ---- GEMM3: [64,256]@[256,16] via 16x16x32; 4 waves own 16-row slices
    {
        f32x4 acc3 = (f32x4){0.f, 0.f, 0.f, 0.f};
        const f16* w3row = W3T + (size_t)l16 * 256 + lq * 8;
        const f16* h2row = smem + (w * 16 + l16) * 264 + lq * 8;
        #pragma unroll
        for (int ks = 0; ks < 8; ++ks) {
            const f16x8 af = *(const f16x8*)(h2row + ks * 32);
            const f16x8 bf = *(const f16x8*)(w3row + ks * 32);
            acc3 = __builtin_amdgcn_mfma_f32_16x16x32_f16(af, bf, acc3, 0, 0, 0);
        }
        const int orow = w * 16 + lq * 4;
        if (!is_speed) {
            if (l16 < 3) {
                const float b3 = bias3[l16];
                #pragma unroll
                for (int r2 = 0; r2 < 4; ++r2) {
                    const int g2 = rowIdx[orow + r2];
                    if (g2 >= 0)
                        out[(size_t)g2 * 3 + l16] = 1.f / (1.f + __expf(-(acc3[r2] + b3)));
                }
            }
        } else if (l16 == 0) {
            const float b3 = bias3[0];
            #pragma unroll
            for (int r2 = 0; r2 < 4; ++r2) {
                const int g2 = rowIdx[orow + r2];
                if (g2 >= 0)
                    out[(size_t)3 * B_ROWS + g2] = acc3[r2] + b3;
            }
        }
    }
}

extern "C" void kernel_launch(void* const* d_in, const int* in_sizes, int n_in,
                              void* d_out, int out_size, void* d_ws, size_t ws_size,
                              hipStream_t stream) {
    (void)in_sizes; (void)n_in; (void)out_size; (void)ws_size;
    const float* embedding = (const float*)d_in[0];
    const float* speed     = (const float*)d_in[1];
    const int*   command   = (const int*)d_in[2];
    const float* si_W1 = (const float*)d_in[3];
    const float* si_b1 = (const float*)d_in[4];
    const float* si_W2 = (const float*)d_in[5];
    const float* si_b2 = (const float*)d_in[6];
    const float* bW1   = (const float*)d_in[7];
    const float* bb1   = (const float*)d_in[8];
    const float* bW2   = (const float*)d_in[9];
    const float* bb2   = (const float*)d_in[10];
    const float* bW3   = (const float*)d_in[11];
    const float* bb3   = (const float*)d_in[12];
    const float* so_W1 = (const float*)d_in[13];
    const float* so_b1 = (const float*)d_in[14];
    const float* so_W2 = (const float*)d_in[15];
    const float* so_b2 = (const float*)d_in[16];
    const float* so_W3 = (const float*)d_in[17];
    const float* so_b3 = (const float*)d_in[18];
    float* out = (float*)d_out;

    char* ws = (char*)d_ws;
    f16* embF16 = (f16*)(ws + OFF_EMBF16);
    f16* siW2T  = (f16*)(ws + OFF_SIW2T);
    f16* bW1T   = (f16*)(ws + OFF_BW1T);
    f16* bW2T   = (f16*)(ws + OFF_BW2T);
    f16* soW1T  = (f16*)(ws + OFF_SOW1T);
    f16* soW2T  = (f16*)(ws + OFF_SOW2T);
    f16* bW3T16 = (f16*)(ws + OFF_BW3T16);
    f16* soW3T16= (f16*)(ws + OFF_SOW3T16);
    int* counts = (int*)(ws + OFF_COUNTS);
    int* cursors= (int*)(ws + OFF_CURSORS);
    int* tile_cmd = (int*)(ws + OFF_TILECMD);
    int* perm   = (int*)(ws + OFF_PERM);

    prep_kernel<<<1859, dim3(32, 8), 0, stream>>>(
        si_W2, bW1, bW2, so_W1, so_W2, bW3, so_W3,
        siW2T, bW1T, bW2T, soW1T, soW2T, bW3T16, soW3T16,
        counts, cursors, perm);
    hist_kernel<<<256, 256, 0, stream>>>(command, counts);
    place_kernel<<<256, 256, 0, stream>>>(command, counts, cursors, perm, tile_cmd);
    pack_kernel<<<NT, 256, 0, stream>>>(
        embedding, speed, si_W1, si_b1, siW2T, si_b2, perm, embF16);
    heads_kernel<<<2 * NT, 256, 0, stream>>>(
        embF16, perm, tile_cmd,
        bW1T, bW2T, bW3T16, bb1, bb2, bb3,
        soW1T, soW2T, soW3T16, so_b1, so_b2, so_b3, out);
}

// Round 8
// 416.750 us; speedup vs baseline: 1.1788x; 1.1292x over previous
//
#include <hip/hip_runtime.h>
#include <cstdint>
#include <cstddef>

typedef _Float16 f16;
typedef f16 f16x8 __attribute__((ext_vector_type(8)));
typedef float f32x4 __attribute__((ext_vector_type(4)));
typedef float f32x16 __attribute__((ext_vector_type(16)));

#define B_ROWS 65536
#define NT 1030                // 64-row tiles incl. bin padding
#define NROWS_P (NT * 64)

// ---------------- ws layout ----------------
constexpr size_t OFF_EMBF16 = 0;
constexpr size_t SZ_EMBF16  = (size_t)B_ROWS * 640 * 2;        // 83,886,080 (original row order)
constexpr size_t OFF_SIW2T  = OFF_EMBF16 + SZ_EMBF16;
constexpr size_t SZ_SIW2T   = (size_t)128 * 256 * 2;
constexpr size_t OFF_BW1T   = OFF_SIW2T + SZ_SIW2T;
constexpr size_t SZ_BW1T    = (size_t)6 * 256 * 640 * 2;
constexpr size_t OFF_BW2T   = OFF_BW1T + SZ_BW1T;
constexpr size_t SZ_BW2T    = (size_t)6 * 256 * 256 * 2;
constexpr size_t OFF_SOW1T  = OFF_BW2T + SZ_BW2T;
constexpr size_t SZ_SOW1T   = (size_t)256 * 640 * 2;
constexpr size_t OFF_SOW2T  = OFF_SOW1T + SZ_SOW1T;
constexpr size_t SZ_SOW2T   = (size_t)256 * 256 * 2;
constexpr size_t OFF_BW3T16 = OFF_SOW2T + SZ_SOW2T;
constexpr size_t SZ_BW3T16  = (size_t)6 * 16 * 256 * 2;
constexpr size_t OFF_SOW3T16= OFF_BW3T16 + SZ_BW3T16;
constexpr size_t SZ_SOW3T16 = (size_t)16 * 256 * 2;
constexpr size_t OFF_COUNTS = OFF_SOW3T16 + SZ_SOW3T16;
constexpr size_t OFF_CURSORS= OFF_COUNTS + 256;
constexpr size_t OFF_TILECMD= OFF_CURSORS + 256;
constexpr size_t OFF_PERM   = OFF_TILECMD + 4352;
constexpr size_t WS_NEEDED  = OFF_PERM + (size_t)NROWS_P * 4;

// async 16B global -> LDS DMA (lane i of the wave lands at ldsbase + 16*i)
__device__ __forceinline__ void gload_lds16(const void* g, void* l) {
    __builtin_amdgcn_global_load_lds(
        (const __attribute__((address_space(1))) unsigned int*)g,
        (__attribute__((address_space(3))) unsigned int*)l, 16, 0, 0);
}

// ---------------- prep: transpose-cast weights + W3T16 + init sort scratch ----------------
__global__ void prep_kernel(const float* __restrict__ siW2,
                            const float* __restrict__ bW1,
                            const float* __restrict__ bW2,
                            const float* __restrict__ soW1,
                            const float* __restrict__ soW2,
                            const float* __restrict__ bW3,
                            const float* __restrict__ soW3,
                            f16* __restrict__ siW2T, f16* __restrict__ bW1T,
                            f16* __restrict__ bW2T, f16* __restrict__ soW1T,
                            f16* __restrict__ soW2T,
                            f16* __restrict__ bW3T16, f16* __restrict__ soW3T16,
                            int* __restrict__ counts, int* __restrict__ cursors,
                            int* __restrict__ perm)
{
    const int bx = blockIdx.x;
    const int tx = threadIdx.x, ty = threadIdx.y;
    const int tid = ty * 32 + tx;
    if (bx >= 1601) {                       // perm init + counter zero
        const int ib = bx - 1601;
        const int idx = ib * 256 + tid;
        if (idx < NROWS_P) perm[idx] = -1;
        if (ib == 0 && tid < 6) { counts[tid] = 0; cursors[tid] = 0; }
        return;
    }
    if (bx == 1600) {                       // W3 -> padded-16-col f16, [n][k] layout
        for (int i = tid; i < 6 * 16 * 256; i += 256) {
            const int c = i >> 12, rem = i & 4095, n = rem >> 8, k = rem & 255;
            bW3T16[i] = (n < 3) ? (f16)bW3[((size_t)c * 256 + k) * 3 + n] : (f16)0;
        }
        for (int i = tid; i < 16 * 256; i += 256) {
            const int n = i >> 8, k = i & 255;
            soW3T16[i] = (n == 0) ? (f16)soW3[k] : (f16)0;
        }
        return;
    }
    const float* in; f16* out; int R, C, lb;
    if (bx < 960)       { int m = bx / 160;        lb = bx - m * 160;       in = bW1 + (size_t)m * 640 * 256; out = bW1T + (size_t)m * 640 * 256; R = 640; C = 256; }
    else if (bx < 1344) { int m = (bx - 960) / 64; lb = (bx - 960) - m * 64; in = bW2 + (size_t)m * 256 * 256; out = bW2T + (size_t)m * 256 * 256; R = 256; C = 256; }
    else if (bx < 1504) { lb = bx - 1344; in = soW1; out = soW1T; R = 640; C = 256; }
    else if (bx < 1568) { lb = bx - 1504; in = soW2; out = soW2T; R = 256; C = 256; }
    else                { lb = bx - 1568; in = siW2; out = siW2T; R = 256; C = 128; }
    const int txt = C >> 5;
    const int c0 = (lb % txt) << 5;
    const int r0 = (lb / txt) << 5;
    __shared__ float tile[32][33];
    #pragma unroll
    for (int i = 0; i < 4; ++i)
        tile[tx][ty + 8 * i] = in[(size_t)(r0 + ty + 8 * i) * C + c0 + tx];
    __syncthreads();
    #pragma unroll
    for (int i = 0; i < 4; ++i)
        out[(size_t)(c0 + ty + 8 * i) * R + r0 + tx] = (f16)tile[ty + 8 * i][tx];
}

// ---------------- pack (+hist): embF16[b] = [cast(emb) | speed_in MLP], original order ----------------
__global__ __launch_bounds__(256) void pack_kernel(
    const float* __restrict__ emb, const float* __restrict__ speed,
    const float* __restrict__ siW1, const float* __restrict__ sib1,
    const f16* __restrict__ siW2T, const float* __restrict__ sib2,
    const int* __restrict__ cmd,
    f16* __restrict__ embF16, int* __restrict__ counts)
{
    __shared__ f16 H[64 * 264];
    __shared__ float spd[64];
    __shared__ int h[6];
    const int tid = threadIdx.x;
    const int rb = blockIdx.x * 64;
    if (tid < 6) h[tid] = 0;
    __syncthreads();
    if (tid < 64) {
        spd[tid] = speed[rb + tid];
        atomicAdd(&h[cmd[rb + tid] - 1], 1);
    }
    __syncthreads();
    if (tid < 6 && h[tid] > 0) atomicAdd(&counts[tid], h[tid]);
    {   // speed_in hidden layer (K=1)
        const float w1 = siW1[tid], b1v = sib1[tid];
        #pragma unroll 4
        for (int r = 0; r < 64; ++r) {
            float hv = spd[r] * w1 + b1v;
            H[r * 264 + tid] = (f16)(hv > 0.f ? hv : 0.f);
        }
    }
    // coalesced cast-copy of cols 0..511
    #pragma unroll
    for (int i = tid; i < 4096; i += 256) {
        const int r = i >> 6, c8 = (i & 63) << 3;
        const float* src = emb + (size_t)(rb + r) * 512 + c8;
        const float4 p0 = *(const float4*)(src);
        const float4 p1 = *(const float4*)(src + 4);
        f16x8 v;
        v[0] = (f16)p0.x; v[1] = (f16)p0.y; v[2] = (f16)p0.z; v[3] = (f16)p0.w;
        v[4] = (f16)p1.x; v[5] = (f16)p1.y; v[6] = (f16)p1.z; v[7] = (f16)p1.w;
        *(f16x8*)(embF16 + (size_t)(rb + r) * 640 + c8) = v;
    }
    __syncthreads();
    // layer 2: [64,256]@[256,128] MFMA -> cols 512..639
    const int w = tid >> 6, lane = tid & 63, lq = lane >> 4, l16 = lane & 15;
    const int nb = w * 32;
    f32x4 acc[4][2];
    #pragma unroll
    for (int mt = 0; mt < 4; ++mt)
        #pragma unroll
        for (int nt = 0; nt < 2; ++nt)
            acc[mt][nt] = (f32x4){0.f, 0.f, 0.f, 0.f};
    for (int ks = 0; ks < 8; ++ks) {
        const int koff = ks * 32 + lq * 8;
        f16x8 af[4], bf[2];
        #pragma unroll
        for (int mt = 0; mt < 4; ++mt)
            af[mt] = *(const f16x8*)(&H[(mt * 16 + l16) * 264 + koff]);
        #pragma unroll
        for (int nt = 0; nt < 2; ++nt)
            bf[nt] = *(const f16x8*)(siW2T + (size_t)(nb + nt * 16 + l16) * 256 + koff);
        #pragma unroll
        for (int mt = 0; mt < 4; ++mt)
            #pragma unroll
            for (int nt = 0; nt < 2; ++nt)
                acc[mt][nt] = __builtin_amdgcn_mfma_f32_16x16x32_f16(af[mt], bf[nt], acc[mt][nt], 0, 0, 0);
    }
    #pragma unroll
    for (int mt = 0; mt < 4; ++mt)
        #pragma unroll
        for (int nt = 0; nt < 2; ++nt) {
            const int n = nb + nt * 16 + l16;
            const float bv = sib2[n];
            #pragma unroll
            for (int r2 = 0; r2 < 4; ++r2) {
                const int m = mt * 16 + lq * 4 + r2;
                embF16[(size_t)(rb + m) * 640 + 512 + n] = (f16)(acc[mt][nt][r2] + bv);
            }
        }
}

// ---------------- place (plan fused): scatter rows into 64-padded bins + tile_cmd ----------------
__global__ void place_kernel(const int* __restrict__ cmd,
                             const int* __restrict__ counts,
                             int* __restrict__ cursors, int* __restrict__ perm,
                             int* __restrict__ tile_cmd) {
    __shared__ int lcnt[6], lbase[6], bb[7];
    const int tid = threadIdx.x;
    if (tid < 6) lcnt[tid] = 0;
    __syncthreads();
    const int i = blockIdx.x * 256 + tid;
    const int c = cmd[i] - 1;
    const int myr = atomicAdd(&lcnt[c], 1);
    if (tid == 0) {
        int base = 0;
        for (int c0 = 0; c0 < 6; ++c0) {
            bb[c0] = base;
            base += ((counts[c0] + 63) >> 6) << 6;
        }
        bb[6] = base;
    }
    __syncthreads();
    if (tid < 6) lbase[tid] = atomicAdd(&cursors[tid], lcnt[tid]);
    __syncthreads();
    perm[bb[c] + lbase[c] + myr] = i;
    if (blockIdx.x == 0) {
        for (int t = tid; t < NT; t += 256) {
            int cc = -1;
            #pragma unroll
            for (int j = 0; j < 6; ++j)
                if (t * 64 >= bb[j] && t * 64 < bb[j + 1]) cc = j;
            tile_cmd[t] = cc;
        }
    }
}

// ---------------- heads: 6-slot ring, burst-of-3 DMA staging, 32x32 MFMA ----------------
// 256 thr = 4 waves; wave w owns N cols w*64..+63; M=64. Pairing: even=branch, odd=speed.
// GEMM1: stage 3 chunks -> barrier -> {issue next 3 DMAs, 48 MFMA} -> barrier ...
// DMA latency covered by the MFMA region; only the first drain is cold.
__global__ __launch_bounds__(256, 3) void heads_kernel(
    const f16* __restrict__ embF16,       // [B,640] original order
    const int* __restrict__ perm, const int* __restrict__ tile_cmd,
    const f16* __restrict__ bW1T, const f16* __restrict__ bW2T,
    const f16* __restrict__ bW3T16,
    const float* __restrict__ bb1, const float* __restrict__ bb2,
    const float* __restrict__ bb3,
    const f16* __restrict__ soW1T, const f16* __restrict__ soW2T,
    const f16* __restrict__ soW3T16,
    const float* __restrict__ sob1, const float* __restrict__ sob2,
    const float* __restrict__ sob3,
    float* __restrict__ out)
{
    __shared__ f16 smem[24576];           // 6 ring slots x 4096 f16; h [64][264] aliases
    const int bx = blockIdx.x, tid = threadIdx.x;
    const int bt = bx >> 1;
    const bool is_speed = (bx & 1);
    const f16 *W1T, *W2T, *W3T;
    const float *bias1, *bias2, *bias3;
    if (is_speed) {
        W1T = soW1T; W2T = soW2T; W3T = soW3T16;
        bias1 = sob1; bias2 = sob2; bias3 = sob3;
    } else {
        const int c = tile_cmd[bt];
        if (c < 0) return;
        W1T = bW1T + (size_t)c * 256 * 640;
        W2T = bW2T + (size_t)c * 256 * 256;
        W3T = bW3T16 + (size_t)c * 16 * 256;
        bias1 = bb1 + c * 256; bias2 = bb2 + c * 256; bias3 = bb3 + c * 3;
    }

    const int w = tid >> 6, lane = tid & 63;
    const int l32 = lane & 31, lq2 = lane >> 5;
    const int l16 = lane & 15, lq = lane >> 4;
    const int nb = w * 64;

    // staging addresses: slot j=round*256+tid holds A[r=j>>3][cg=(j&7)^(r&7)] (XOR swizzle)
    const int r0s = tid >> 3, cg0 = (tid & 7) ^ (r0s & 7);
    const int r1s = 32 + r0s, cg1 = (tid & 7) ^ (r1s & 7);
    int g0 = perm[bt * 64 + r0s]; if (g0 < 0) g0 = 0;
    int g1 = perm[bt * 64 + r1s]; if (g1 < 0) g1 = 0;
    const f16* gsrc0 = embF16 + (size_t)g0 * 640 + cg0 * 8;
    const f16* gsrc1 = embF16 + (size_t)g1 * 640 + cg1 * 8;
    const int ldsW = (tid & 192) * 8;     // wave-uniform LDS base (f16 idx)

    const f16* bpr0 = W1T + (size_t)(nb + l32) * 640 + lq2 * 8;
    const f16* bpr1 = bpr0 + (size_t)32 * 640;

    f32x16 acc[2][2];
    #pragma unroll
    for (int mi = 0; mi < 2; ++mi)
        #pragma unroll
        for (int ni = 0; ni < 2; ++ni)
            #pragma unroll
            for (int i = 0; i < 16; ++i)
                acc[mi][ni][i] = 0.f;

#define STAGE(kc, slot)                                                  \
    do {                                                                 \
        gload_lds16((const void*)(gsrc0 + (kc) * 64),                    \
                    (void*)(smem + (slot) * 4096 + ldsW));               \
        gload_lds16((const void*)(gsrc1 + (kc) * 64),                    \
                    (void*)(smem + (slot) * 4096 + 2048 + ldsW));        \
    } while (0)

#define CHUNK(kc, slot)                                                          \
    do {                                                                         \
        const f16* cur = smem + (slot) * 4096;                                   \
        _Pragma("unroll")                                                        \
        for (int s = 0; s < 4; ++s) {                                            \
            const int cs = ((2 * s + lq2) ^ (l32 & 7)) * 8;                      \
            const f16x8 a0 = *(const f16x8*)(cur + l32 * 64 + cs);               \
            const f16x8 a1 = *(const f16x8*)(cur + 2048 + l32 * 64 + cs);        \
            const f16x8 b0 = *(const f16x8*)(bpr0 + (kc) * 64 + s * 16);         \
            const f16x8 b1 = *(const f16x8*)(bpr1 + (kc) * 64 + s * 16);         \
            acc[0][0] = __builtin_amdgcn_mfma_f32_32x32x16_f16(a0, b0, acc[0][0], 0, 0, 0); \
            acc[1][0] = __builtin_amdgcn_mfma_f32_32x32x16_f16(a1, b0, acc[1][0], 0, 0, 0); \
            acc[0][1] = __builtin_amdgcn_mfma_f32_32x32x16_f16(a0, b1, acc[0][1], 0, 0, 0); \
            acc[1][1] = __builtin_amdgcn_mfma_f32_32x32x16_f16(a1, b1, acc[1][1], 0, 0, 0); \
        }                                                                        \
    } while (0)

    STAGE(0, 0); STAGE(1, 1); STAGE(2, 2);
    __syncthreads();
    STAGE(3, 3); STAGE(4, 4); STAGE(5, 5);
    CHUNK(0, 0); CHUNK(1, 1); CHUNK(2, 2);
    __syncthreads();
    STAGE(6, 0); STAGE(7, 1); STAGE(8, 2);
    CHUNK(3, 3); CHUNK(4, 4); CHUNK(5, 5);
    __syncthreads();
    STAGE(9, 3);
    CHUNK(6, 0); CHUNK(7, 1); CHUNK(8, 2);
    __syncthreads();
    CHUNK(9, 3);
    __syncthreads();
#undef STAGE
#undef CHUNK

    // h1 = relu(acc + b1) -> smem [64][264]; 32x32 C-layout
    {
        const float b1v0 = bias1[nb + l32], b1v1 = bias1[nb + 32 + l32];
        #pragma unroll
        for (int mi = 0; mi < 2; ++mi)
            #pragma unroll
            for (int rg = 0; rg < 16; ++rg) {
                const int m = 32 * mi + (rg & 3) + 8 * (rg >> 2) + 4 * lq2;
                const float v0 = acc[mi][0][rg] + b1v0;
                const float v1 = acc[mi][1][rg] + b1v1;
                smem[m * 264 + nb + l32]      = (f16)(v0 > 0.f ? v0 : 0.f);
                smem[m * 264 + nb + 32 + l32] = (f16)(v1 > 0.f ? v1 : 0.f);
            }
    }
    __syncthreads();

    // ---- GEMM2: K=256, A=h1 (LDS), 16 steps, no barriers
    f32x16 d[2][2];
    #pragma unroll
    for (int mi = 0; mi < 2; ++mi)
        #pragma unroll
        for (int ni = 0; ni < 2; ++ni)
            #pragma unroll
            for (int i = 0; i < 16; ++i)
                d[mi][ni][i] = 0.f;
    const f16* cpr0 = W2T + (size_t)(nb + l32) * 256 + lq2 * 8;
    const f16* cpr1 = cpr0 + (size_t)32 * 256;
    const f16* h0 = smem + l32 * 264 + lq2 * 8;
    const f16* h1p = smem + (32 + l32) * 264 + lq2 * 8;
    #pragma unroll
    for (int s = 0; s < 16; ++s) {
        const f16x8 a0 = *(const f16x8*)(h0 + s * 16);
        const f16x8 a1 = *(const f16x8*)(h1p + s * 16);
        const f16x8 b0 = *(const f16x8*)(cpr0 + s * 16);
        const f16x8 b1 = *(const f16x8*)(cpr1 + s * 16);
        d[0][0] = __builtin_amdgcn_mfma_f32_32x32x16_f16(a0, b0, d[0][0], 0, 0, 0);
        d[1][0] = __builtin_amdgcn_mfma_f32_32x32x16_f16(a1, b0, d[1][0], 0, 0, 0);
        d[0][1] = __builtin_amdgcn_mfma_f32_32x32x16_f16(a0, b1, d[0][1], 0, 0, 0);
        d[1][1] = __builtin_amdgcn_mfma_f32_32x32x16_f16(a1, b1, d[1][1], 0, 0, 0);
    }
    __syncthreads();
    // h2 = relu(d + b2) -> smem
    {
        const float b2v0 = bias2[nb + l32], b2v1 = bias2[nb + 32 + l32];
        #pragma unroll
        for (int mi = 0; mi < 2; ++mi)
            #pragma unroll
            for (int rg = 0; rg < 16; ++rg) {
                const int m = 32 * mi + (rg & 3) + 8 * (rg >> 2) + 4 * lq2;
                const float v0 = d[mi][0][rg] + b2v0;
                const float v1 = d[mi][1][rg] + b2v1;
                smem[m * 264 + nb + l32]      = (f16)(v0 > 0.f ? v0 : 0.f);
                smem[m * 264 + nb + 32 + l32] = (f16)(v1 > 0.f ? v1 : 0.f);
            }
    }
    __syncthreads();
    // ---- GEMM3: [64,256]@[256,16] via 16x16x32; 4 waves own 16-row slices
    {
        f32x4 acc3 = (f32x4){0.f, 0.f, 0.f, 0.f};
        const f16* w3row = W3T + (size_t)l16 * 256 + lq * 8;
        const f16* h2row = smem + (w * 16 + l16) * 264 + lq * 8;
        #pragma unroll
        for (int ks = 0; ks < 8; ++ks) {
            const f16x8 af = *(const f16x8*)(h2row + ks * 32);
            const f16x8 bf = *(const f16x8*)(w3row + ks * 32);
            acc3 = __builtin_amdgcn_mfma_f32_16x16x32_f16(af, bf, acc3, 0, 0, 0);
        }
        const int orow = w * 16 + lq * 4;
        if (!is_speed) {
            if (l16 < 3) {
                const float b3 = bias3[l16];
                #pragma unroll
                for (int r2 = 0; r2 < 4; ++r2) {
                    const int g2 = perm[bt * 64 + orow + r2];
                    if (g2 >= 0)
                        out[(size_t)g2 * 3 + l16] = 1.f / (1.f + __expf(-(acc3[r2] + b3)));
                }
            }
        } else if (l16 == 0) {
            const float b3 = bias3[0];
            #pragma unroll
            for (int r2 = 0; r2 < 4; ++r2) {
                const int g2 = perm[bt * 64 + orow + r2];
                if (g2 >= 0)
                    out[(size_t)3 * B_ROWS + g2] = acc3[r2] + b3;
            }
        }
    }
}

extern "C" void kernel_launch(void* const* d_in, const int* in_sizes, int n_in,
                              void* d_out, int out_size, void* d_ws, size_t ws_size,
                              hipStream_t stream) {
    (void)in_sizes; (void)n_in; (void)out_size; (void)ws_size;
    const float* embedding = (const float*)d_in[0];
    const float* speed     = (const float*)d_in[1];
    const int*   command   = (const int*)d_in[2];
    const float* si_W1 = (const float*)d_in[3];
    const float* si_b1 = (const float*)d_in[4];
    const float* si_W2 = (const float*)d_in[5];
    const float* si_b2 = (const float*)d_in[6];
    const float* bW1   = (const float*)d_in[7];
    const float* bb1   = (const float*)d_in[8];
    const float* bW2   = (const float*)d_in[9];
    const float* bb2   = (const float*)d_in[10];
    const float* bW3   = (const float*)d_in[11];
    const float* bb3   = (const float*)d_in[12];
    const float* so_W1 = (const float*)d_in[13];
    const float* so_b1 = (const float*)d_in[14];
    const float* so_W2 = (const float*)d_in[15];
    const float* so_b2 = (const float*)d_in[16];
    const float* so_W3 = (const float*)d_in[17];
    const float* so_b3 = (const float*)d_in[18];
    float* out = (float*)d_out;

    char* ws = (char*)d_ws;
    f16* embF16 = (f16*)(ws + OFF_EMBF16);
    f16* siW2T  = (f16*)(ws + OFF_SIW2T);
    f16* bW1T   = (f16*)(ws + OFF_BW1T);
    f16* bW2T   = (f16*)(ws + OFF_BW2T);
    f16* soW1T  = (f16*)(ws + OFF_SOW1T);
    f16* soW2T  = (f16*)(ws + OFF_SOW2T);
    f16* bW3T16 = (f16*)(ws + OFF_BW3T16);
    f16* soW3T16= (f16*)(ws + OFF_SOW3T16);
    int* counts = (int*)(ws + OFF_COUNTS);
    int* cursors= (int*)(ws + OFF_CURSORS);
    int* tile_cmd = (int*)(ws + OFF_TILECMD);
    int* perm   = (int*)(ws + OFF_PERM);

    prep_kernel<<<1859, dim3(32, 8), 0, stream>>>(
        si_W2, bW1, bW2, so_W1, so_W2, bW3, so_W3,
        siW2T, bW1T, bW2T, soW1T, soW2T, bW3T16, soW3T16,
        counts, cursors, perm);
    pack_kernel<<<1024, 256, 0, stream>>>(
        embedding, speed, si_W1, si_b1, siW2T, si_b2, command, embF16, counts);
    place_kernel<<<256, 256, 0, stream>>>(command, counts, cursors, perm, tile_cmd);
    heads_kernel<<<2 * NT, 256, 0, stream>>>(
        embF16, perm, tile_cmd,
        bW1T, bW2T, bW3T16, bb1, bb2, bb3,
        soW1T, soW2T, soW3T16, so_b1, so_b2, so_b3, out);
}